// Round 3
// baseline (72.441 us; speedup 1.0000x reference)
//
#include <hip/hip_runtime.h>
#include <math.h>

#define B_  2
#define N_  2048
#define NT_ 8
#define DZ_ 16
#define H_  64
#define W_  64

#define XGRID_SIZE (B_*NT_*H_*W_*3)   // 196608 floats
#define CUT 12.0f                     // keep if dt^2+di^2 < 12 (w > 2.4e-4)
#define CH  128                       // K-chunk: 4 waves x K=32

using half8   = __attribute__((ext_vector_type(8))) _Float16;
using floatx4 = __attribute__((ext_vector_type(4))) float;

#if __has_builtin(__builtin_amdgcn_exp2f)
#define EXP2(xx) __builtin_amdgcn_exp2f(xx)
#else
#define EXP2(xx) exp2f(xx)
#endif

// ---------------------------------------------------------------------------
// R14 = R13 (69.5) + j-split for occupancy (latency-bound theory).
//
// R13 post-mortem: prediction matched (phase-1 prefix compaction -2.4 us).
// Issue-throughput model of the whole kernel sums to <=8 us but measured
// portion is ~29 us above the fill floor -> latency/occupancy-bound at
// 4 waves/SIMD (the 268 MB poison fill flushes L2/L3, so every phase's
// first-touch is a ~900 cy HBM miss that 4 waves/SIMD cannot hide).
//
// Changes vs R13:
//  * grid 1024 -> 2048: block owns a 32-wide j-half (2 MFMA tiles, not 4).
//    Per-block critical path ~halves; phase-1 cull duplicated (+~1.5 us
//    total, known-cheap after R13).
//  * meta packed to 8 B/entry: entry index embedded in the low 11 bits of
//    s's mantissa (abs err <= 2^-9 on s -> <=0.14% on the weight, far under
//    the existing f16 noise). cidx[] deleted: LDS 26.1 -> 17.4 KB.
//  * __launch_bounds__(256,6): 6 blocks/CU (24 waves/CU). Phase-2 live set
//    halved, est. ~70 VGPR peak < 84 cap.
//
// Phase 1 (validated R13): 6 dwordx4 x-loads, ballot-decomposed prefix
// compaction, no atomics. Phase 2 (validated R11/R13 structure): wave w
// owns k-subrange [w*32,w*32+32) of each 128-chunk, B-frag gathered from
// global z (64 B coalesced/quad, L2-resident), 1-chunk-deep z prefetch,
// NO barriers in the K-loop. Epilogue: stride-17 LDS reduce, float4 store.
// ---------------------------------------------------------------------------
__global__ __launch_bounds__(256, 6) void fused_kernel(
    const float* __restrict__ x,      // [B][N][3]
    const float* __restrict__ z,      // [B][N][16]
    const float* __restrict__ tg,     // [B][NT]
    const float* __restrict__ lsp,    // [3]
    float* __restrict__ out)          // x_grid (196608) ++ z_grid (1048576)
{
    const int jh   = blockIdx.x & 1;       // j-half: js in [jh*32, jh*32+32)
    const int rid  = blockIdx.x >> 1;      // 0..1023: (b,t,i) row
    const int i    = rid & 63;
    const int t    = (rid >> 6) & 7;
    const int b    = rid >> 9;
    const int tid  = threadIdx.x;
    const int w    = tid >> 6;        // wave id = k-subrange
    const int lane = tid & 63;
    const int quad = lane >> 4;       // 0..3
    const int col  = lane & 15;       // A row (j in tile) / B col (e)

    const float step = 2.0f / 63.0f;
    const float C    = 0.84932180f;   // sqrt(0.5 * log2(e))

    const float r0 = C / (1e-5f + log1pf(expf(lsp[0])));
    const float r1 = C / (1e-5f + log1pf(expf(lsp[1])));
    const float r2 = C / (1e-5f + log1pf(expf(lsp[2])));

    const float tval = tg[b*NT_ + t];
    const float gi   = -1.0f + step * (float)i;

    union REDU {
        float2 cuc[N_ + CH];           // {s|idx, cx}: 17408 B (phases 1-2)
        float  red[4][32][DZ_ + 1];    // 8704 B (epilogue reduce)
    };
    __shared__ REDU sm;
    __shared__ int  wsum[4];

    // ---- phase 1: cull + prefix-sum compaction (no atomics) ----
    const float* __restrict__ xb = x + b*N_*3;
    float sq[8], cx[8];
    int keepm = 0;
    {
        const float4* __restrict__ xb4 = (const float4*)xb;
        float f[24];
        #pragma unroll
        for (int q = 0; q < 6; ++q) {
            float4 v = xb4[tid*6 + q];
            f[q*4+0] = v.x; f[q*4+1] = v.y; f[q*4+2] = v.z; f[q*4+3] = v.w;
        }
        #pragma unroll
        for (int r = 0; r < 8; ++r) {
            float dt = (tval - f[3*r+0]) * r0;
            float di = (gi   - f[3*r+1]) * r1;
            sq[r] = fmaf(dt, dt, di*di);
            cx[r] = f[3*r+2] * r2;
            if (sq[r] < CUT) keepm |= (1 << r);
        }
    }
    const int cnt = __popc(keepm);
    // ballot-decomposed exclusive prefix over the wave (cnt in [0,8])
    const unsigned long long below = (1ull << lane) - 1ull;
    int pre = 0, wtot = 0;
    #pragma unroll
    for (int bit = 0; bit < 4; ++bit) {
        unsigned long long bb = __ballot((cnt >> bit) & 1);
        pre  += __popcll(bb & below) << bit;
        wtot += __popcll(bb) << bit;
    }
    if (lane == 0) wsum[w] = wtot;
    __syncthreads();

    int woff = 0, M = 0;
    #pragma unroll
    for (int ww = 0; ww < 4; ++ww) {
        int s = wsum[ww];
        woff += (ww < w) ? s : 0;
        M    += s;
    }
    {
        int pos = woff + pre;
        #pragma unroll
        for (int r = 0; r < 8; ++r) {
            if ((keepm >> r) & 1) {
                // embed entry index in low 11 mantissa bits of s
                unsigned int sb = (__float_as_uint(sq[r]) & ~2047u)
                                | (unsigned int)(tid*8 + r);
                sm.cuc[pos] = make_float2(__uint_as_float(sb), cx[r]);
                ++pos;
            }
        }
    }
    // pad: disjoint from scatter ([M, M+CH)); s huge -> exp2 -> 0
    // (1e9f low-11 bits decode to idx 808 < 2048: valid, harmless gather)
    if (tid < CH) sm.cuc[M + tid] = make_float2(1e9f, 0.f);

    // x_grid: this block writes its 96-float half of the 192-float row
    if (tid < 96) {
        int e  = jh*96 + tid;
        int jj = e / 3;
        int c  = e - jj*3;
        float gj = -1.0f + step * (float)jj;
        float v  = (c == 0) ? tval : ((c == 1) ? gi : gj);
        out[(size_t)rid * 192 + e] = v;
    }
    __syncthreads();

    const int NC = (M + CH - 1) / CH;  // 128-entry chunks

    // ---- phase 2: barrier-free MFMA K-loop, 2 j-tiles ----
    const float* __restrict__ zb = z + b*N_*DZ_;
    const int koff = w*32 + (quad << 3);   // this lane's k-base within a chunk

    const float ajA = (-1.0f + step * (float)(jh*32 +  0 + col)) * r2;
    const float ajB = (-1.0f + step * (float)(jh*32 + 16 + col)) * r2;

    floatx4 acc0 = {0.f,0.f,0.f,0.f};
    floatx4 acc1 = {0.f,0.f,0.f,0.f};

    // prologue: B dwords for chunk 0 (pads make indices always valid)
    float zreg[8];
    {
        #pragma unroll
        for (int jj = 0; jj < 8; ++jj) {
            unsigned int u = __float_as_uint(sm.cuc[koff + jj].x) & 2047u;
            zreg[jj] = zb[(size_t)u * DZ_ + col];
        }
    }

    for (int c = 0; c < NC; ++c) {
        // pack current B fragment
        half8 bf;
        #pragma unroll
        for (int jj = 0; jj < 8; ++jj) bf[jj] = (_Float16)zreg[jj];

        // meta for current chunk (quad-uniform broadcast, 8 entries/lane)
        const int base = c*CH + koff;
        float2 mm[8];
        #pragma unroll
        for (int jj = 0; jj < 8; ++jj) mm[jj] = sm.cuc[base + jj];

        // prefetch next chunk's B dwords (land during exp/MFMA below)
        if (c + 1 < NC) {
            const int base2 = (c + 1)*CH + koff;
            #pragma unroll
            for (int jj = 0; jj < 8; ++jj) {
                unsigned int u = __float_as_uint(sm.cuc[base2 + jj].x) & 2047u;
                zreg[jj] = zb[(size_t)u * DZ_ + col];
            }
        }

        // A fragments for the 2 j-tiles (s carries +<=2^-9 idx noise: ok)
        half8 a0, a1;
        #pragma unroll
        for (int jj = 0; jj < 8; ++jj) {
            float s   = mm[jj].x;
            float cxv = mm[jj].y;
            float d0 = ajA - cxv;
            float d1 = ajB - cxv;
            a0[jj] = (_Float16)EXP2(-fmaf(d0, d0, s));
            a1[jj] = (_Float16)EXP2(-fmaf(d1, d1, s));
        }

        acc0 = __builtin_amdgcn_mfma_f32_16x16x32_f16(a0, bf, acc0, 0, 0, 0);
        acc1 = __builtin_amdgcn_mfma_f32_16x16x32_f16(a1, bf, acc1, 0, 0, 0);
    }

    __syncthreads();   // all cuc reads done before red overlays it

    // ---- epilogue: reduce 4 k-partials across waves, store z_grid half ----
    // D layout: row = quad*4 + reg, col = lane&15.
    #pragma unroll
    for (int r = 0; r < 4; ++r) sm.red[w][ 0 + quad*4 + r][col] = acc0[r];
    #pragma unroll
    for (int r = 0; r < 4; ++r) sm.red[w][16 + quad*4 + r][col] = acc1[r];
    __syncthreads();

    if (tid < 128) {
        const int jj = tid >> 2;           // 0..31 (j within half)
        const int eg = (tid & 3) * 4;      // 0,4,8,12
        float4 s4 = make_float4(0.f, 0.f, 0.f, 0.f);
        #pragma unroll
        for (int ww = 0; ww < 4; ++ww) {
            s4.x += sm.red[ww][jj][eg + 0];
            s4.y += sm.red[ww][jj][eg + 1];
            s4.z += sm.red[ww][jj][eg + 2];
            s4.w += sm.red[ww][jj][eg + 3];
        }
        float* og = out + XGRID_SIZE + (size_t)rid * (W_ * DZ_) + jh * (32 * DZ_);
        *(float4*)(og + jj*DZ_ + eg) = s4;
    }
}

extern "C" void kernel_launch(void* const* d_in, const int* in_sizes, int n_in,
                              void* d_out, int out_size, void* d_ws, size_t ws_size,
                              hipStream_t stream) {
    const float* x   = (const float*)d_in[0];   // [B][N][3]
    const float* z   = (const float*)d_in[1];   // [B][N][16]
    const float* tg  = (const float*)d_in[2];   // [B][NT]
    const float* lsp = (const float*)d_in[3];   // [3]

    float* out = (float*)d_out;

    // 2048 blocks: (b,t,i) x j-half; no workspace, no memset, no atomics.
    fused_kernel<<<2048, 256, 0, stream>>>(x, z, tg, lsp, out);
}

// Round 4
// 69.086 us; speedup vs baseline: 1.0486x; 1.0486x over previous
//
#include <hip/hip_runtime.h>
#include <math.h>

#define B_  2
#define N_  2048
#define NT_ 8
#define DZ_ 16
#define H_  64
#define W_  64

#define XGRID_SIZE (B_*NT_*H_*W_*3)   // 196608 floats
#define CUT 12.0f                     // keep if dt^2+di^2 < 12 (w > 2.4e-4)
#define CH  128                       // K-chunk: 4 waves x K=32

using half8   = __attribute__((ext_vector_type(8))) _Float16;
using floatx4 = __attribute__((ext_vector_type(4))) float;

#if __has_builtin(__builtin_amdgcn_exp2f)
#define EXP2(xx) __builtin_amdgcn_exp2f(xx)
#else
#define EXP2(xx) exp2f(xx)
#endif

// ---------------------------------------------------------------------------
// R15 = R13 (best, 69.5) + i-spread swizzle + 8B meta + (256,5).
//
// R14 post-mortem (j-split, 72.4): confounded test. Doubling phase-1 work
// cost ~2.5 us (calibrates R13 phase 1 at ~2.5 us total) and the (256,6)
// VGPR cap (~85) likely spilled. Occupancy was never cleanly tested.
// Salvaged: 8B meta pack ran on HW with absmax bit-identical -> validated.
//
// Changes vs R13 (phase-2 structure untouched):
//  * i-spread swizzle: old i = bid&63 gave each CU 4 co-resident blocks of
//    the SAME i (spacing 256); M(i) varies ~1.7x edge->center, so central-i
//    CUs were 4x-heavy stragglers. New mapping i=bid>>4, t=(bid>>1)&7,
//    b=bid&1: a CU's blocks span {i,i+16,i+32,i+48} -> per-CU work ~= mean.
//    Free: every block reads all of x/z regardless, no locality change.
//  * 8B meta (R14-validated): entry idx in low 11 mantissa bits of s
//    (abs err <= 2^-9 on s -> <= 0.14% on weight, under f16 noise).
//    cidx[] deleted: LDS 26.1 -> 17.4 KB, 8 fewer LDS reads per chunk.
//  * __launch_bounds__(256,5): 5 blocks/CU (LDS 87 KB < 160; VGPR cap
//    ~102 > est. ~90 live set -- deliberately NOT R14's 85 cap). All 1024
//    blocks co-resident (capacity 1280): no dispatch rounds.
//
// Phase 1 (validated R13): 6 dwordx4 x-loads, ballot-decomposed prefix
// compaction, no atomics. Phase 2 (validated R11/R13): wave w owns
// k-subrange [w*32,w*32+32) of each 128-chunk, 4 j-tiles from one B-frag
// gathered from global z (64 B coalesced/quad, L2-resident), 1-chunk-deep
// z prefetch, NO barriers in the K-loop. Epilogue: stride-17 LDS reduce,
// coalesced float4 stores. No atomics anywhere.
// ---------------------------------------------------------------------------
__global__ __launch_bounds__(256, 5) void fused_kernel(
    const float* __restrict__ x,      // [B][N][3]
    const float* __restrict__ z,      // [B][N][16]
    const float* __restrict__ tg,     // [B][NT]
    const float* __restrict__ lsp,    // [3]
    float* __restrict__ out)          // x_grid (196608) ++ z_grid (1048576)
{
    const int bid  = blockIdx.x;
    const int i    = bid >> 4;            // i varies across co-resident blocks
    const int t    = (bid >> 1) & 7;
    const int b    = bid & 1;
    const int rid  = (b << 9) | (t << 6) | i;   // canonical (b,t,i) row
    const int tid  = threadIdx.x;
    const int w    = tid >> 6;        // wave id = k-subrange
    const int lane = tid & 63;
    const int quad = lane >> 4;       // 0..3
    const int col  = lane & 15;       // A row (j in tile) / B col (e)

    const float step = 2.0f / 63.0f;
    const float C    = 0.84932180f;   // sqrt(0.5 * log2(e))

    const float r0 = C / (1e-5f + log1pf(expf(lsp[0])));
    const float r1 = C / (1e-5f + log1pf(expf(lsp[1])));
    const float r2 = C / (1e-5f + log1pf(expf(lsp[2])));

    const float tval = tg[b*NT_ + t];
    const float gi   = -1.0f + step * (float)i;

    union REDU {
        float2 cuc[N_ + CH];           // {s|idx, cx}: 17408 B (phases 1-2)
        float  red[4][64][DZ_ + 1];    // 17408 B (epilogue reduce)
    };
    __shared__ REDU sm;
    __shared__ int  wsum[4];

    // ---- phase 1: cull + prefix-sum compaction (no atomics) ----
    // Thread owns 8 consecutive entries k = tid*8 + r -> x rows load as
    // 6 float4s (96 B/thread, one vmcnt window).
    const float* __restrict__ xb = x + b*N_*3;
    float sq[8], cx[8];
    int keepm = 0;
    {
        const float4* __restrict__ xb4 = (const float4*)xb;
        float f[24];
        #pragma unroll
        for (int q = 0; q < 6; ++q) {
            float4 v = xb4[tid*6 + q];
            f[q*4+0] = v.x; f[q*4+1] = v.y; f[q*4+2] = v.z; f[q*4+3] = v.w;
        }
        #pragma unroll
        for (int r = 0; r < 8; ++r) {
            float dt = (tval - f[3*r+0]) * r0;
            float di = (gi   - f[3*r+1]) * r1;
            sq[r] = fmaf(dt, dt, di*di);
            cx[r] = f[3*r+2] * r2;
            if (sq[r] < CUT) keepm |= (1 << r);
        }
    }
    const int cnt = __popc(keepm);
    // ballot-decomposed exclusive prefix over the wave (cnt in [0,8])
    const unsigned long long below = (1ull << lane) - 1ull;
    int pre = 0, wtot = 0;
    #pragma unroll
    for (int bit = 0; bit < 4; ++bit) {
        unsigned long long bb = __ballot((cnt >> bit) & 1);
        pre  += __popcll(bb & below) << bit;
        wtot += __popcll(bb) << bit;
    }
    if (lane == 0) wsum[w] = wtot;
    __syncthreads();

    int woff = 0, M = 0;
    #pragma unroll
    for (int ww = 0; ww < 4; ++ww) {
        int s = wsum[ww];
        woff += (ww < w) ? s : 0;
        M    += s;
    }
    {
        int pos = woff + pre;
        #pragma unroll
        for (int r = 0; r < 8; ++r) {
            if ((keepm >> r) & 1) {
                // embed entry index in low 11 mantissa bits of s
                unsigned int sb = (__float_as_uint(sq[r]) & ~2047u)
                                | (unsigned int)(tid*8 + r);
                sm.cuc[pos] = make_float2(__uint_as_float(sb), cx[r]);
                ++pos;
            }
        }
    }
    // pad: disjoint from scatter ([M, M+CH)); s huge -> exp2 -> 0
    // (1e9f low-11 bits decode to idx 808 < 2048: valid, harmless gather)
    if (tid < CH) sm.cuc[M + tid] = make_float2(1e9f, 0.f);

    // x_grid row for this (b,t,i): 192 floats, coalesced
    if (tid < 192) {
        int jj = tid / 3;
        int c  = tid - jj*3;
        float gj = -1.0f + step * (float)jj;
        float v  = (c == 0) ? tval : ((c == 1) ? gi : gj);
        out[(size_t)rid * 192 + tid] = v;
    }
    __syncthreads();

    const int NC = (M + CH - 1) / CH;  // 128-entry chunks

    // ---- phase 2: barrier-free MFMA K-loop ----
    const float* __restrict__ zb = z + b*N_*DZ_;
    const int koff = w*32 + (quad << 3);   // this lane's k-base within a chunk

    const float aj0 = (-1.0f + step * (float)( 0 + col)) * r2;
    const float aj1 = (-1.0f + step * (float)(16 + col)) * r2;
    const float aj2 = (-1.0f + step * (float)(32 + col)) * r2;
    const float aj3 = (-1.0f + step * (float)(48 + col)) * r2;

    floatx4 acc0 = {0.f,0.f,0.f,0.f};
    floatx4 acc1 = {0.f,0.f,0.f,0.f};
    floatx4 acc2 = {0.f,0.f,0.f,0.f};
    floatx4 acc3 = {0.f,0.f,0.f,0.f};

    // prologue: B dwords for chunk 0 (pads make indices always valid)
    float zreg[8];
    {
        #pragma unroll
        for (int jj = 0; jj < 8; ++jj) {
            unsigned int u = __float_as_uint(sm.cuc[koff + jj].x) & 2047u;
            zreg[jj] = zb[(size_t)u * DZ_ + col];
        }
    }

    for (int c = 0; c < NC; ++c) {
        // pack current B fragment
        half8 bf;
        #pragma unroll
        for (int jj = 0; jj < 8; ++jj) bf[jj] = (_Float16)zreg[jj];

        // meta for current chunk (quad-uniform broadcast, 8 entries/lane)
        const int base = c*CH + koff;
        float2 mm[8];
        #pragma unroll
        for (int jj = 0; jj < 8; ++jj) mm[jj] = sm.cuc[base + jj];

        // prefetch next chunk's B dwords (land during exp/MFMA below)
        if (c + 1 < NC) {
            const int base2 = (c + 1)*CH + koff;
            #pragma unroll
            for (int jj = 0; jj < 8; ++jj) {
                unsigned int u = __float_as_uint(sm.cuc[base2 + jj].x) & 2047u;
                zreg[jj] = zb[(size_t)u * DZ_ + col];
            }
        }

        // A fragments for the 4 j-tiles (s carries +<=2^-9 idx noise: ok)
        half8 a0, a1, a2, a3;
        #pragma unroll
        for (int jj = 0; jj < 8; ++jj) {
            float s   = mm[jj].x;
            float cxv = mm[jj].y;
            float d0 = aj0 - cxv;
            float d1 = aj1 - cxv;
            float d2 = aj2 - cxv;
            float d3 = aj3 - cxv;
            a0[jj] = (_Float16)EXP2(-fmaf(d0, d0, s));
            a1[jj] = (_Float16)EXP2(-fmaf(d1, d1, s));
            a2[jj] = (_Float16)EXP2(-fmaf(d2, d2, s));
            a3[jj] = (_Float16)EXP2(-fmaf(d3, d3, s));
        }

        acc0 = __builtin_amdgcn_mfma_f32_16x16x32_f16(a0, bf, acc0, 0, 0, 0);
        acc1 = __builtin_amdgcn_mfma_f32_16x16x32_f16(a1, bf, acc1, 0, 0, 0);
        acc2 = __builtin_amdgcn_mfma_f32_16x16x32_f16(a2, bf, acc2, 0, 0, 0);
        acc3 = __builtin_amdgcn_mfma_f32_16x16x32_f16(a3, bf, acc3, 0, 0, 0);
    }

    __syncthreads();   // all cuc reads done before red overlays it

    // ---- epilogue: reduce 4 k-partials across waves, store z_grid ----
    // D layout: row = quad*4 + reg, col = lane&15.
    #pragma unroll
    for (int r = 0; r < 4; ++r) sm.red[w][ 0 + quad*4 + r][col] = acc0[r];
    #pragma unroll
    for (int r = 0; r < 4; ++r) sm.red[w][16 + quad*4 + r][col] = acc1[r];
    #pragma unroll
    for (int r = 0; r < 4; ++r) sm.red[w][32 + quad*4 + r][col] = acc2[r];
    #pragma unroll
    for (int r = 0; r < 4; ++r) sm.red[w][48 + quad*4 + r][col] = acc3[r];
    __syncthreads();

    const int jj = tid >> 2;               // 0..63
    const int eg = (tid & 3) * 4;          // 0,4,8,12
    float4 s4 = make_float4(0.f, 0.f, 0.f, 0.f);
    #pragma unroll
    for (int ww = 0; ww < 4; ++ww) {
        s4.x += sm.red[ww][jj][eg + 0];
        s4.y += sm.red[ww][jj][eg + 1];
        s4.z += sm.red[ww][jj][eg + 2];
        s4.w += sm.red[ww][jj][eg + 3];
    }
    float* og = out + XGRID_SIZE + (size_t)rid * (W_ * DZ_);
    *(float4*)(og + jj*DZ_ + eg) = s4;
}

extern "C" void kernel_launch(void* const* d_in, const int* in_sizes, int n_in,
                              void* d_out, int out_size, void* d_ws, size_t ws_size,
                              hipStream_t stream) {
    const float* x   = (const float*)d_in[0];   // [B][N][3]
    const float* z   = (const float*)d_in[1];   // [B][N][16]
    const float* tg  = (const float*)d_in[2];   // [B][NT]
    const float* lsp = (const float*)d_in[3];   // [3]

    float* out = (float*)d_out;

    // 1024 blocks, one per (b,t,i) row (i-spread swizzled); no workspace,
    // no memset, no atomics.
    fused_kernel<<<1024, 256, 0, stream>>>(x, z, tg, lsp, out);
}

// Round 5
// 68.786 us; speedup vs baseline: 1.0531x; 1.0044x over previous
//
#include <hip/hip_runtime.h>
#include <math.h>

#define B_  2
#define N_  2048
#define NT_ 8
#define DZ_ 16
#define H_  64
#define W_  64

#define XGRID_SIZE (B_*NT_*H_*W_*3)   // 196608 floats
#define CUT 12.0f                     // keep if dt^2+di^2 < 12 (w > 2.4e-4)
#define CH  128                       // K-chunk: 4 waves x K=32

using half8   = __attribute__((ext_vector_type(8))) _Float16;
using floatx4 = __attribute__((ext_vector_type(4))) float;

#if __has_builtin(__builtin_amdgcn_exp2f)
#define EXP2(xx) __builtin_amdgcn_exp2f(xx)
#else
#define EXP2(xx) exp2f(xx)
#endif

// ---------------------------------------------------------------------------
// R16 = R15 (69.1) with the VGPR cap removed + setprio on the compute cluster.
//
// R15 post-mortem: straggler swizzle + (256,5) + 8B meta = -0.46 us (noise).
// Two readings: (a) (256,5)'s ~102-VGPR cap spilled the ~91-reg phase-2
// live set, masking the straggler gain (repeat of R14's confound, softer);
// (b) the controllable kernel fraction is already small (~6-8 us of the
// ~29 us residual; the rest fill + fixed harness overhead -- fused_kernel
// never appears in the counter top-5, only 40-us fills do).
// R16 decides between them:
//  * back to __launch_bounds__(256,4): the only spill-free-validated config.
//    If (a), straggler gain appears now.
//  * s_setprio(1) around the exp+MFMA cluster (T5): co-resident blocks here
//    are independent and phase-staggered -- the regime where setprio paid
//    in attn (m191). Prefers compute-issuing waves over gather-issuing ones.
//  * keeps: i-spread swizzle (per-CU load balance), 8B meta (idx in low 11
//    mantissa bits of s; absmax bit-identical on HW), ballot-prefix phase 1,
//    barrier-free K-loop, stride-17 reduce.
// If flat at ~69: controllable portion exhausted; floor = fill 40.3 +
// fixed overhead ~20 + kernel ~7 -> declare ceiling.
// ---------------------------------------------------------------------------
__global__ __launch_bounds__(256, 4) void fused_kernel(
    const float* __restrict__ x,      // [B][N][3]
    const float* __restrict__ z,      // [B][N][16]
    const float* __restrict__ tg,     // [B][NT]
    const float* __restrict__ lsp,    // [3]
    float* __restrict__ out)          // x_grid (196608) ++ z_grid (1048576)
{
    const int bid  = blockIdx.x;
    const int i    = bid >> 4;            // i varies across co-resident blocks
    const int t    = (bid >> 1) & 7;
    const int b    = bid & 1;
    const int rid  = (b << 9) | (t << 6) | i;   // canonical (b,t,i) row
    const int tid  = threadIdx.x;
    const int w    = tid >> 6;        // wave id = k-subrange
    const int lane = tid & 63;
    const int quad = lane >> 4;       // 0..3
    const int col  = lane & 15;       // A row (j in tile) / B col (e)

    const float step = 2.0f / 63.0f;
    const float C    = 0.84932180f;   // sqrt(0.5 * log2(e))

    const float r0 = C / (1e-5f + log1pf(expf(lsp[0])));
    const float r1 = C / (1e-5f + log1pf(expf(lsp[1])));
    const float r2 = C / (1e-5f + log1pf(expf(lsp[2])));

    const float tval = tg[b*NT_ + t];
    const float gi   = -1.0f + step * (float)i;

    union REDU {
        float2 cuc[N_ + CH];           // {s|idx, cx}: 17408 B (phases 1-2)
        float  red[4][64][DZ_ + 1];    // 17408 B (epilogue reduce)
    };
    __shared__ REDU sm;
    __shared__ int  wsum[4];

    // ---- phase 1: cull + prefix-sum compaction (no atomics) ----
    // Thread owns 8 consecutive entries k = tid*8 + r -> x rows load as
    // 6 float4s (96 B/thread, one vmcnt window).
    const float* __restrict__ xb = x + b*N_*3;
    float sq[8], cx[8];
    int keepm = 0;
    {
        const float4* __restrict__ xb4 = (const float4*)xb;
        float f[24];
        #pragma unroll
        for (int q = 0; q < 6; ++q) {
            float4 v = xb4[tid*6 + q];
            f[q*4+0] = v.x; f[q*4+1] = v.y; f[q*4+2] = v.z; f[q*4+3] = v.w;
        }
        #pragma unroll
        for (int r = 0; r < 8; ++r) {
            float dt = (tval - f[3*r+0]) * r0;
            float di = (gi   - f[3*r+1]) * r1;
            sq[r] = fmaf(dt, dt, di*di);
            cx[r] = f[3*r+2] * r2;
            if (sq[r] < CUT) keepm |= (1 << r);
        }
    }
    const int cnt = __popc(keepm);
    // ballot-decomposed exclusive prefix over the wave (cnt in [0,8])
    const unsigned long long below = (1ull << lane) - 1ull;
    int pre = 0, wtot = 0;
    #pragma unroll
    for (int bit = 0; bit < 4; ++bit) {
        unsigned long long bb = __ballot((cnt >> bit) & 1);
        pre  += __popcll(bb & below) << bit;
        wtot += __popcll(bb) << bit;
    }
    if (lane == 0) wsum[w] = wtot;
    __syncthreads();

    int woff = 0, M = 0;
    #pragma unroll
    for (int ww = 0; ww < 4; ++ww) {
        int s = wsum[ww];
        woff += (ww < w) ? s : 0;
        M    += s;
    }
    {
        int pos = woff + pre;
        #pragma unroll
        for (int r = 0; r < 8; ++r) {
            if ((keepm >> r) & 1) {
                // embed entry index in low 11 mantissa bits of s
                unsigned int sb = (__float_as_uint(sq[r]) & ~2047u)
                                | (unsigned int)(tid*8 + r);
                sm.cuc[pos] = make_float2(__uint_as_float(sb), cx[r]);
                ++pos;
            }
        }
    }
    // pad: disjoint from scatter ([M, M+CH)); s huge -> exp2 -> 0
    // (1e9f low-11 bits decode to idx 808 < 2048: valid, harmless gather)
    if (tid < CH) sm.cuc[M + tid] = make_float2(1e9f, 0.f);

    // x_grid row for this (b,t,i): 192 floats, coalesced
    if (tid < 192) {
        int jj = tid / 3;
        int c  = tid - jj*3;
        float gj = -1.0f + step * (float)jj;
        float v  = (c == 0) ? tval : ((c == 1) ? gi : gj);
        out[(size_t)rid * 192 + tid] = v;
    }
    __syncthreads();

    const int NC = (M + CH - 1) / CH;  // 128-entry chunks

    // ---- phase 2: barrier-free MFMA K-loop ----
    const float* __restrict__ zb = z + b*N_*DZ_;
    const int koff = w*32 + (quad << 3);   // this lane's k-base within a chunk

    const float aj0 = (-1.0f + step * (float)( 0 + col)) * r2;
    const float aj1 = (-1.0f + step * (float)(16 + col)) * r2;
    const float aj2 = (-1.0f + step * (float)(32 + col)) * r2;
    const float aj3 = (-1.0f + step * (float)(48 + col)) * r2;

    floatx4 acc0 = {0.f,0.f,0.f,0.f};
    floatx4 acc1 = {0.f,0.f,0.f,0.f};
    floatx4 acc2 = {0.f,0.f,0.f,0.f};
    floatx4 acc3 = {0.f,0.f,0.f,0.f};

    // prologue: B dwords for chunk 0 (pads make indices always valid)
    float zreg[8];
    {
        #pragma unroll
        for (int jj = 0; jj < 8; ++jj) {
            unsigned int u = __float_as_uint(sm.cuc[koff + jj].x) & 2047u;
            zreg[jj] = zb[(size_t)u * DZ_ + col];
        }
    }

    for (int c = 0; c < NC; ++c) {
        // pack current B fragment
        half8 bf;
        #pragma unroll
        for (int jj = 0; jj < 8; ++jj) bf[jj] = (_Float16)zreg[jj];

        // meta for current chunk (quad-uniform broadcast, 8 entries/lane)
        const int base = c*CH + koff;
        float2 mm[8];
        #pragma unroll
        for (int jj = 0; jj < 8; ++jj) mm[jj] = sm.cuc[base + jj];

        // prefetch next chunk's B dwords (land during exp/MFMA below)
        if (c + 1 < NC) {
            const int base2 = (c + 1)*CH + koff;
            #pragma unroll
            for (int jj = 0; jj < 8; ++jj) {
                unsigned int u = __float_as_uint(sm.cuc[base2 + jj].x) & 2047u;
                zreg[jj] = zb[(size_t)u * DZ_ + col];
            }
        }

        // compute cluster: prefer this wave while it issues exp+MFMA (T5;
        // co-resident independent blocks are phase-staggered here)
        __builtin_amdgcn_s_setprio(1);

        // A fragments for the 4 j-tiles (s carries +<=2^-9 idx noise: ok)
        half8 a0, a1, a2, a3;
        #pragma unroll
        for (int jj = 0; jj < 8; ++jj) {
            float s   = mm[jj].x;
            float cxv = mm[jj].y;
            float d0 = aj0 - cxv;
            float d1 = aj1 - cxv;
            float d2 = aj2 - cxv;
            float d3 = aj3 - cxv;
            a0[jj] = (_Float16)EXP2(-fmaf(d0, d0, s));
            a1[jj] = (_Float16)EXP2(-fmaf(d1, d1, s));
            a2[jj] = (_Float16)EXP2(-fmaf(d2, d2, s));
            a3[jj] = (_Float16)EXP2(-fmaf(d3, d3, s));
        }

        acc0 = __builtin_amdgcn_mfma_f32_16x16x32_f16(a0, bf, acc0, 0, 0, 0);
        acc1 = __builtin_amdgcn_mfma_f32_16x16x32_f16(a1, bf, acc1, 0, 0, 0);
        acc2 = __builtin_amdgcn_mfma_f32_16x16x32_f16(a2, bf, acc2, 0, 0, 0);
        acc3 = __builtin_amdgcn_mfma_f32_16x16x32_f16(a3, bf, acc3, 0, 0, 0);

        __builtin_amdgcn_s_setprio(0);
    }

    __syncthreads();   // all cuc reads done before red overlays it

    // ---- epilogue: reduce 4 k-partials across waves, store z_grid ----
    // D layout: row = quad*4 + reg, col = lane&15.
    #pragma unroll
    for (int r = 0; r < 4; ++r) sm.red[w][ 0 + quad*4 + r][col] = acc0[r];
    #pragma unroll
    for (int r = 0; r < 4; ++r) sm.red[w][16 + quad*4 + r][col] = acc1[r];
    #pragma unroll
    for (int r = 0; r < 4; ++r) sm.red[w][32 + quad*4 + r][col] = acc2[r];
    #pragma unroll
    for (int r = 0; r < 4; ++r) sm.red[w][48 + quad*4 + r][col] = acc3[r];
    __syncthreads();

    const int jj = tid >> 2;               // 0..63
    const int eg = (tid & 3) * 4;          // 0,4,8,12
    float4 s4 = make_float4(0.f, 0.f, 0.f, 0.f);
    #pragma unroll
    for (int ww = 0; ww < 4; ++ww) {
        s4.x += sm.red[ww][jj][eg + 0];
        s4.y += sm.red[ww][jj][eg + 1];
        s4.z += sm.red[ww][jj][eg + 2];
        s4.w += sm.red[ww][jj][eg + 3];
    }
    float* og = out + XGRID_SIZE + (size_t)rid * (W_ * DZ_);
    *(float4*)(og + jj*DZ_ + eg) = s4;
}

extern "C" void kernel_launch(void* const* d_in, const int* in_sizes, int n_in,
                              void* d_out, int out_size, void* d_ws, size_t ws_size,
                              hipStream_t stream) {
    const float* x   = (const float*)d_in[0];   // [B][N][3]
    const float* z   = (const float*)d_in[1];   // [B][N][16]
    const float* tg  = (const float*)d_in[2];   // [B][NT]
    const float* lsp = (const float*)d_in[3];   // [3]

    float* out = (float*)d_out;

    // 1024 blocks, one per (b,t,i) row (i-spread swizzled); no workspace,
    // no memset, no atomics.
    fused_kernel<<<1024, 256, 0, stream>>>(x, z, tg, lsp, out);
}